// Round 2
// baseline (17832.706 us; speedup 1.0000x reference)
//
#include <hip/hip_runtime.h>

#define BB 64
#define NN 1000
#define FF 12
#define EE 64
#define HH 128
#define OO 16
#define GG 512

__device__ __forceinline__ float rcp_(float x){ return __builtin_amdgcn_rcpf(x); }
__device__ __forceinline__ float sigm_(float x){ return rcp_(1.0f + __expf(-x)); }
// exact algebraic form of tanh: (e^{2x}-1)/(e^{2x}+1) = 1 - 2/(e^{2x}+1)
__device__ __forceinline__ float tanh_(float x){ return 1.0f - 2.0f*rcp_(__expf(2.0f*x) + 1.0f); }

__global__ __launch_bounds__(512, 1)
void decoder_kernel(const float* __restrict__ enc,   // (B,1,N,E)
                    const float* __restrict__ mean,  // (B,FUT,N,O)
                    const float* __restrict__ sv,    // (1,O)
                    const float* __restrict__ h0,    // (2,O)
                    const float* __restrict__ c0,    // (2,H)
                    const float* __restrict__ Wih0,  // (G, E+O)
                    const float* __restrict__ Whh0,  // (G, O)
                    const float* __restrict__ bih0,  // (G)
                    const float* __restrict__ bhh0,  // (G)
                    const float* __restrict__ Whr0,  // (O, H)
                    const float* __restrict__ Wih1,  // (G, O)
                    const float* __restrict__ Whh1,  // (G, O)
                    const float* __restrict__ bih1,  // (G)
                    const float* __restrict__ bhh1,  // (G)
                    const float* __restrict__ Whr1,  // (O, H)
                    float* __restrict__ out)         // (B,FUT,N,O)
{
    const int t = threadIdx.x;   // gate index for both layers
    const int b = blockIdx.x;    // batch chain

    __shared__ __align__(16) float s_gates[GG];
    __shared__ __align__(16) float s_c1[2][HH];   // ping-pong cell state
    __shared__ __align__(16) float s_c2[2][HH];
    __shared__ __align__(16) float s_h1[OO];
    __shared__ __align__(16) float s_h2[OO];
    __shared__ __align__(16) float s_last[OO];
    __shared__ __align__(16) float s_enc[EE];
    __shared__ __align__(16) float s_nm[OO];

    // ---- per-thread weights in registers (1 gate per thread, both layers) ----
    float w_enc[EE];                       // W_ih0[t, 0:64]  (enc part, per-node)
    float w_loop[OO], w_hh0[OO], w_ih1[OO], w_hh1[OO];
    {
        const float* r = Wih0 + t*(EE+OO);
        #pragma unroll
        for (int e=0;e<EE;e++) w_enc[e] = r[e];
        #pragma unroll
        for (int j=0;j<OO;j++) w_loop[j] = r[EE+j];
        #pragma unroll
        for (int j=0;j<OO;j++) w_hh0[j] = Whh0[t*OO+j];
        #pragma unroll
        for (int j=0;j<OO;j++) w_ih1[j] = Wih1[t*OO+j];
        #pragma unroll
        for (int j=0;j<OO;j++) w_hh1[j] = Whh1[t*OO+j];
    }
    const float bias0 = bih0[t] + bhh0[t];
    const float bias1 = bih1[t] + bhh1[t];

    // projection mapping: output j16 = t>>5, units kb..kb+3 with kb=(t&31)*4
    const int j16  = t >> 5;
    const int lane = t & 31;
    const int kb   = lane * 4;
    float wp0[4], wp1[4];
    #pragma unroll
    for (int u=0;u<4;u++){
        wp0[u] = Whr0[j16*HH + kb + u];
        wp1[u] = Whr1[j16*HH + kb + u];
    }

    if (t < OO){
        s_last[t] = sv[t];        // last0 = s[0]
        s_h1[t]   = h0[t];        // h_0[0]
        s_h2[t]   = h0[OO + t];   // h_0[1]
    }
    if (t < 32){
        #pragma unroll
        for (int u=0;u<4;u++){
            s_c1[0][t*4+u] = c0[t*4+u];
            s_c2[0][t*4+u] = c0[HH + t*4+u];
        }
    }
    __syncthreads();

    const float* encB  = enc  + (size_t)b * NN * EE;
    const float* meanB = mean + (size_t)b * FF * NN * OO;
    float*       outB  = out  + (size_t)b * FF * NN * OO;

    const bool isTanhGate = ((t >> 7) == 2);   // gates[256:384] are 'g' -> tanh

    for (int n = 0; n < NN; ++n){
        // ---- per-node loads: enc_t and node_mean ----
        if (t < EE){
            s_enc[t] = encB[n*EE + t];
        } else if (t < EE + OO){
            const int j = t - EE;
            float a = 0.0f;
            #pragma unroll
            for (int f=0; f<FF; ++f) a += meanB[(f*NN + n)*OO + j];
            s_nm[j] = a * (1.0f/12.0f);
        }
        __syncthreads();                                       // B0 (per node)

        // per-node constant part of layer-0 gate t
        float pre0 = bias0;
        #pragma unroll
        for (int e=0;e<EE;e++) pre0 += s_enc[e]*w_enc[e];
        #pragma unroll
        for (int j=0;j<OO;j++) pre0 += s_nm[j]*w_loop[j];
        const float nm_j = s_nm[j16];

        int par = 0;   // FF=12 is even, so parity resets each node

        for (int f=0; f<FF; ++f){
            // ---- P1: layer-0 gates (activated) ----
            float acc = pre0;
            #pragma unroll
            for (int j=0;j<OO;j++) acc += s_last[j]*w_loop[j];
            #pragma unroll
            for (int j=0;j<OO;j++) acc += s_h1[j]*w_hh0[j];
            s_gates[t] = isTanhGate ? tanh_(acc) : sigm_(acc);
            __syncthreads();                                   // B1

            // ---- P2: layer-0 cell + projection fused ----
            {
                const float4 gi = *reinterpret_cast<const float4*>(&s_gates[kb]);
                const float4 gf = *reinterpret_cast<const float4*>(&s_gates[HH + kb]);
                const float4 gg = *reinterpret_cast<const float4*>(&s_gates[2*HH + kb]);
                const float4 go = *reinterpret_cast<const float4*>(&s_gates[3*HH + kb]);
                float4 cv = *reinterpret_cast<const float4*>(&s_c1[par][kb]);
                cv.x = gf.x*cv.x + gi.x*gg.x;
                cv.y = gf.y*cv.y + gi.y*gg.y;
                cv.z = gf.z*cv.z + gi.z*gg.z;
                cv.w = gf.w*cv.w + gi.w*gg.w;
                float p = go.x*tanh_(cv.x)*wp0[0]
                        + go.y*tanh_(cv.y)*wp0[1]
                        + go.z*tanh_(cv.z)*wp0[2]
                        + go.w*tanh_(cv.w)*wp0[3];
                p += __shfl_down(p, 16, 32);
                p += __shfl_down(p,  8, 32);
                p += __shfl_down(p,  4, 32);
                p += __shfl_down(p,  2, 32);
                p += __shfl_down(p,  1, 32);
                if (lane == 0) s_h1[j16] = p;
                if (t < 32) *reinterpret_cast<float4*>(&s_c1[par^1][t*4]) = cv;
            }
            __syncthreads();                                   // B2

            // ---- P3: layer-1 gates (activated) ----
            float acc1 = bias1;
            #pragma unroll
            for (int j=0;j<OO;j++) acc1 += s_h1[j]*w_ih1[j];
            #pragma unroll
            for (int j=0;j<OO;j++) acc1 += s_h2[j]*w_hh1[j];
            s_gates[t] = isTanhGate ? tanh_(acc1) : sigm_(acc1);
            __syncthreads();                                   // B3

            // ---- P4: layer-1 cell + projection fused + output ----
            {
                const float4 gi = *reinterpret_cast<const float4*>(&s_gates[kb]);
                const float4 gf = *reinterpret_cast<const float4*>(&s_gates[HH + kb]);
                const float4 gg = *reinterpret_cast<const float4*>(&s_gates[2*HH + kb]);
                const float4 go = *reinterpret_cast<const float4*>(&s_gates[3*HH + kb]);
                float4 cv = *reinterpret_cast<const float4*>(&s_c2[par][kb]);
                cv.x = gf.x*cv.x + gi.x*gg.x;
                cv.y = gf.y*cv.y + gi.y*gg.y;
                cv.z = gf.z*cv.z + gi.z*gg.z;
                cv.w = gf.w*cv.w + gi.w*gg.w;
                float p = go.x*tanh_(cv.x)*wp1[0]
                        + go.y*tanh_(cv.y)*wp1[1]
                        + go.z*tanh_(cv.z)*wp1[2]
                        + go.w*tanh_(cv.w)*wp1[3];
                p += __shfl_down(p, 16, 32);
                p += __shfl_down(p,  8, 32);
                p += __shfl_down(p,  4, 32);
                p += __shfl_down(p,  2, 32);
                p += __shfl_down(p,  1, 32);
                if (lane == 0){
                    s_h2[j16]   = p;
                    s_last[j16] = p;
                    outB[(f*NN + n)*OO + j16] = p + nm_j;
                }
                if (t < 32) *reinterpret_cast<float4*>(&s_c2[par^1][t*4]) = cv;
            }
            __syncthreads();                                   // B4

            par ^= 1;
        }
    }
}

extern "C" void kernel_launch(void* const* d_in, const int* in_sizes, int n_in,
                              void* d_out, int out_size, void* d_ws, size_t ws_size,
                              hipStream_t stream) {
    const float* enc  = (const float*)d_in[0];
    const float* mean = (const float*)d_in[1];
    const float* sv   = (const float*)d_in[2];
    const float* h0   = (const float*)d_in[3];
    const float* c0   = (const float*)d_in[4];
    const float* Wih0 = (const float*)d_in[5];
    const float* Whh0 = (const float*)d_in[6];
    const float* bih0 = (const float*)d_in[7];
    const float* bhh0 = (const float*)d_in[8];
    const float* Whr0 = (const float*)d_in[9];
    const float* Wih1 = (const float*)d_in[10];
    const float* Whh1 = (const float*)d_in[11];
    const float* bih1 = (const float*)d_in[12];
    const float* bhh1 = (const float*)d_in[13];
    const float* Whr1 = (const float*)d_in[14];
    float* out = (float*)d_out;

    decoder_kernel<<<dim3(BB), dim3(512), 0, stream>>>(
        enc, mean, sv, h0, c0,
        Wih0, Whh0, bih0, bhh0, Whr0,
        Wih1, Whh1, bih1, bhh1, Whr1,
        out);
}

// Round 3
// 16140.945 us; speedup vs baseline: 1.1048x; 1.1048x over previous
//
#include <hip/hip_runtime.h>

#define BB 64
#define NN 1000
#define FF 12
#define EE 64
#define HH 128
#define OO 16

__device__ __forceinline__ float rcp_(float x){ return __builtin_amdgcn_rcpf(x); }
__device__ __forceinline__ float sigm_(float x){ return rcp_(1.0f + __expf(-x)); }
// exact algebraic form of tanh: (e^{2x}-1)/(e^{2x}+1) = 1 - 2/(e^{2x}+1)
__device__ __forceinline__ float tanh_(float x){ return 1.0f - 2.0f*rcp_(__expf(2.0f*x) + 1.0f); }

// 256 threads = 4 waves = 1 wave/SIMD (cheap barriers, no co-issue interference).
// Lane pair (2u, 2u+1) owns LSTM unit u: even lane computes gates i,g; odd lane f,o.
// Gates never go through LDS: one shfl_xor(1) exchange inside the pair, cell state
// c[u] replicated in both lanes' registers. 4 barriers/step instead of 6.
__global__ __launch_bounds__(256, 1)
void decoder_kernel(const float* __restrict__ enc,   // (B,1,N,E)
                    const float* __restrict__ mean,  // (B,FUT,N,O)
                    const float* __restrict__ sv,    // (1,O)
                    const float* __restrict__ h0,    // (2,O)
                    const float* __restrict__ c0,    // (2,H)
                    const float* __restrict__ Wih0,  // (4H, E+O)
                    const float* __restrict__ Whh0,  // (4H, O)
                    const float* __restrict__ bih0,  // (4H)
                    const float* __restrict__ bhh0,  // (4H)
                    const float* __restrict__ Whr0,  // (O, H)
                    const float* __restrict__ Wih1,  // (4H, O)
                    const float* __restrict__ Whh1,  // (4H, O)
                    const float* __restrict__ bih1,  // (4H)
                    const float* __restrict__ bhh1,  // (4H)
                    const float* __restrict__ Whr1,  // (O, H)
                    float* __restrict__ out)         // (B,FUT,N,O)
{
    const int t = threadIdx.x;
    const int b = blockIdx.x;

    const int u  = t >> 1;        // LSTM unit 0..127
    const int m  = t & 1;         // 0: gates i,g   1: gates f,o
    const int rA = m*HH + u;      // row of gate A (i or f)
    const int rB = m*HH + 2*HH + u; // row of gate B (g or o)

    // projection mapping: output j16 = t>>4, k-chunk kc..kc+7
    const int j16 = t >> 4;
    const int kq  = t & 15;
    const int kc  = kq * 8;

    __shared__ __align__(16) float s_hfull[HH];
    __shared__ __align__(16) float s_h1[OO];
    __shared__ __align__(16) float s_h2[OO];
    __shared__ __align__(16) float s_last[OO];
    __shared__ __align__(16) float s_enc[EE];
    __shared__ __align__(16) float s_nm[OO];

    // ---- per-thread weights in registers ----
    float wAe[EE], wBe[EE];                 // enc parts of Wih0 rows rA,rB
    float wAl[OO], wBl[OO];                 // loop (last+nm) parts
    float wAh[OO], wBh[OO];                 // Whh0 rows
    float w1Ai[OO], w1Bi[OO];               // Wih1 rows
    float w1Ah[OO], w1Bh[OO];               // Whh1 rows
    {
        const float* ra = Wih0 + (size_t)rA*(EE+OO);
        const float* rb = Wih0 + (size_t)rB*(EE+OO);
        #pragma unroll
        for (int e=0;e<EE;e++){ wAe[e]=ra[e]; wBe[e]=rb[e]; }
        #pragma unroll
        for (int j=0;j<OO;j++){ wAl[j]=ra[EE+j]; wBl[j]=rb[EE+j]; }
        #pragma unroll
        for (int j=0;j<OO;j++){ wAh[j]=Whh0[rA*OO+j]; wBh[j]=Whh0[rB*OO+j]; }
        #pragma unroll
        for (int j=0;j<OO;j++){ w1Ai[j]=Wih1[rA*OO+j]; w1Bi[j]=Wih1[rB*OO+j]; }
        #pragma unroll
        for (int j=0;j<OO;j++){ w1Ah[j]=Whh1[rA*OO+j]; w1Bh[j]=Whh1[rB*OO+j]; }
    }
    const float b0A = bih0[rA] + bhh0[rA];
    const float b0B = bih0[rB] + bhh0[rB];
    const float b1A = bih1[rA] + bhh1[rA];
    const float b1B = bih1[rB] + bhh1[rB];

    float wp0[8], wp1[8];
    #pragma unroll
    for (int k=0;k<8;k++){
        wp0[k] = Whr0[j16*HH + kc + k];
        wp1[k] = Whr1[j16*HH + kc + k];
    }

    // replicated cell state (both lanes of a pair hold unit u)
    float c1u = c0[u];
    float c2u = c0[HH + u];

    if (t < OO){
        s_last[t] = sv[t];
        s_h1[t]   = h0[t];
        s_h2[t]   = h0[OO + t];
    }

    const float* encB  = enc  + (size_t)b * NN * EE;
    const float* meanB = mean + (size_t)b * FF * NN * OO;
    float*       outB  = out  + (size_t)b * FF * NN * OO;

    // ---- prefetch node 0 into registers ----
    float4 pf_enc = make_float4(0.f,0.f,0.f,0.f);
    float  pf_nm[FF];
    if (t < 16){
        pf_enc = ((const float4*)encB)[t];
    } else if (t < 32){
        const int j = t - 16;
        #pragma unroll
        for (int ff=0; ff<FF; ++ff) pf_nm[ff] = meanB[(ff*NN + 0)*OO + j];
    }
    __syncthreads();

    for (int n = 0; n < NN; ++n){
        // commit prefetched node data to LDS
        if (t < 16){
            ((float4*)s_enc)[t] = pf_enc;
        } else if (t < 32){
            float a = 0.0f;
            #pragma unroll
            for (int ff=0; ff<FF; ++ff) a += pf_nm[ff];
            s_nm[t-16] = a * (1.0f/12.0f);
        }
        __syncthreads();                                   // B0 (per node)

        // issue prefetch for node n+1 (overlaps the next 12 steps)
        const int n1 = (n+1 < NN) ? (n+1) : n;
        if (t < 16){
            pf_enc = ((const float4*)encB)[n1*16 + t];
        } else if (t < 32){
            const int j = t - 16;
            #pragma unroll
            for (int ff=0; ff<FF; ++ff) pf_nm[ff] = meanB[(ff*NN + n1)*OO + j];
        }

        // per-node constant gate pre-activation (enc + node_mean parts)
        float preA = b0A, preB = b0B;
        #pragma unroll
        for (int e=0;e<EE;e++){ const float ev = s_enc[e]; preA += ev*wAe[e]; preB += ev*wBe[e]; }
        #pragma unroll
        for (int j=0;j<OO;j++){ const float nv = s_nm[j]; preA += nv*wAl[j]; preB += nv*wBl[j]; }
        const float nmj = s_nm[j16];

        #pragma unroll 1
        for (int f = 0; f < FF; ++f){
            // ---- P1: layer-0 gates + cell (pair-fused, no LDS for gates) ----
            {
                float aA = preA, aB = preB;
                #pragma unroll
                for (int j=0;j<OO;j++){ const float lv = s_last[j]; aA += lv*wAl[j]; aB += lv*wBl[j]; }
                #pragma unroll
                for (int j=0;j<OO;j++){ const float hv = s_h1[j];   aA += hv*wAh[j]; aB += hv*wBh[j]; }
                const float gA = sigm_(aA);                         // i (m=0) or f (m=1)
                const float gB = (m==0) ? tanh_(aB) : sigm_(aB);    // g (m=0) or o (m=1)
                const float sendv = (m==0) ? gA*gB : gA;            // even sends i*g, odd sends f
                const float recvv = __shfl_xor(sendv, 1, 64);
                const float Fv   = (m==0) ? recvv : sendv;
                const float prod = (m==0) ? sendv : recvv;
                c1u = Fv*c1u + prod;
                if (m==1) s_hfull[u] = gB * tanh_(c1u);             // o * tanh(c_new)
            }
            __syncthreads();                               // B1

            // ---- P2: projection h1 = Whr0 . hfull ----
            {
                const float4 ha = *(const float4*)&s_hfull[kc];
                const float4 hb = *(const float4*)&s_hfull[kc+4];
                float p = ha.x*wp0[0] + ha.y*wp0[1] + ha.z*wp0[2] + ha.w*wp0[3]
                        + hb.x*wp0[4] + hb.y*wp0[5] + hb.z*wp0[6] + hb.w*wp0[7];
                p += __shfl_xor(p, 8, 64);
                p += __shfl_xor(p, 4, 64);
                p += __shfl_xor(p, 2, 64);
                p += __shfl_xor(p, 1, 64);
                if (kq == 0) s_h1[j16] = p;
            }
            __syncthreads();                               // B2

            // ---- P3: layer-1 gates + cell ----
            {
                float aA = b1A, aB = b1B;
                #pragma unroll
                for (int j=0;j<OO;j++){ const float hv = s_h1[j]; aA += hv*w1Ai[j]; aB += hv*w1Bi[j]; }
                #pragma unroll
                for (int j=0;j<OO;j++){ const float hv = s_h2[j]; aA += hv*w1Ah[j]; aB += hv*w1Bh[j]; }
                const float gA = sigm_(aA);
                const float gB = (m==0) ? tanh_(aB) : sigm_(aB);
                const float sendv = (m==0) ? gA*gB : gA;
                const float recvv = __shfl_xor(sendv, 1, 64);
                const float Fv   = (m==0) ? recvv : sendv;
                const float prod = (m==0) ? sendv : recvv;
                c2u = Fv*c2u + prod;
                if (m==1) s_hfull[u] = gB * tanh_(c2u);
            }
            __syncthreads();                               // B3

            // ---- P4: projection h2 = Whr1 . hfull, output, state update ----
            {
                const float4 ha = *(const float4*)&s_hfull[kc];
                const float4 hb = *(const float4*)&s_hfull[kc+4];
                float p = ha.x*wp1[0] + ha.y*wp1[1] + ha.z*wp1[2] + ha.w*wp1[3]
                        + hb.x*wp1[4] + hb.y*wp1[5] + hb.z*wp1[6] + hb.w*wp1[7];
                p += __shfl_xor(p, 8, 64);
                p += __shfl_xor(p, 4, 64);
                p += __shfl_xor(p, 2, 64);
                p += __shfl_xor(p, 1, 64);
                if (kq == 0){
                    s_h2[j16]   = p;
                    s_last[j16] = p;
                    outB[(f*NN + n)*OO + j16] = p + nmj;
                }
            }
            __syncthreads();                               // B4
        }
    }
}

extern "C" void kernel_launch(void* const* d_in, const int* in_sizes, int n_in,
                              void* d_out, int out_size, void* d_ws, size_t ws_size,
                              hipStream_t stream) {
    const float* enc  = (const float*)d_in[0];
    const float* mean = (const float*)d_in[1];
    const float* sv   = (const float*)d_in[2];
    const float* h0   = (const float*)d_in[3];
    const float* c0   = (const float*)d_in[4];
    const float* Wih0 = (const float*)d_in[5];
    const float* Whh0 = (const float*)d_in[6];
    const float* bih0 = (const float*)d_in[7];
    const float* bhh0 = (const float*)d_in[8];
    const float* Whr0 = (const float*)d_in[9];
    const float* Wih1 = (const float*)d_in[10];
    const float* Whh1 = (const float*)d_in[11];
    const float* bih1 = (const float*)d_in[12];
    const float* bhh1 = (const float*)d_in[13];
    const float* Whr1 = (const float*)d_in[14];
    float* out = (float*)d_out;

    decoder_kernel<<<dim3(BB), dim3(256), 0, stream>>>(
        enc, mean, sv, h0, c0,
        Wih0, Whh0, bih0, bhh0, Whr0,
        Wih1, Whh1, bih1, bhh1, Whr1,
        out);
}